// Round 3
// baseline (108.942 us; speedup 1.0000x reference)
//
#include <hip/hip_runtime.h>

// Problem constants
#define BB 8
#define CI 64
#define CO 64
#define NV 40962
#define KN 7
#define KKD 448   // CI*KN

typedef unsigned short u16;
typedef unsigned int u32;

typedef __bf16 bf16x8 __attribute__((ext_vector_type(8)));
typedef float f32x16 __attribute__((ext_vector_type(16)));

__device__ inline u16 f2bf(float f) {
    u32 u = __builtin_bit_cast(u32, f);
    u32 r = (u + 0x7FFFu + ((u >> 16) & 1u)) >> 16;  // RNE
    return (u16)r;
}

// global 16B -> LDS at (wave-uniform base + lane*16); dest must be linear.
__device__ inline void gload_lds16(const void* g, void* l) {
    __builtin_amdgcn_global_load_lds(
        (const __attribute__((address_space(1))) u32*)g,
        (__attribute__((address_space(3))) u32*)l, 16, 0, 0);
}

// ---------------------------------------------------------------------------
// Kernel 1: transpose + bf16 cast:  x[b][c][n] f32  ->  xT[b][n][c] bf16
// ---------------------------------------------------------------------------
__global__ void transpose_x(const float* __restrict__ x, u16* __restrict__ xT) {
    __shared__ u16 tile[64][72];
    const int b = blockIdx.y;
    const int n0 = blockIdx.x * 64;
    const int tid = threadIdx.x;

#pragma unroll
    for (int i = 0; i < 16; ++i) {
        int flat = i * 256 + tid;
        int c = flat >> 6;
        int nn = flat & 63;
        int n = n0 + nn;
        if (n < NV) {
            float v = __builtin_nontemporal_load(&x[((size_t)b * CI + c) * NV + n]);
            tile[nn][c] = f2bf(v);
        }
    }
    __syncthreads();

#pragma unroll
    for (int i = 0; i < 2; ++i) {
        int flat8 = i * 256 + tid;
        int nn = flat8 >> 3;
        int c0 = (flat8 & 7) * 8;
        int n = n0 + nn;
        if (n < NV) {
            uint4 v = *(const uint4*)&tile[nn][c0];
            *(uint4*)&xT[((size_t)b * NV + n) * CI + c0] = v;
        }
    }
}

// ---------------------------------------------------------------------------
// Kernel 2: pack W into MFMA A-fragment order (bf16)  [unchanged layout]
// Wf byte offset (rg*28 + s)*1024 + lane*16, s = k*4 + sub
// ---------------------------------------------------------------------------
__global__ void pack_w(const float* __restrict__ W, u16* __restrict__ Wf) {
    int e = blockIdx.x * 256 + threadIdx.x;
    if (e < 2 * 28 * 64 * 8) {
        int j = e & 7;
        int lane = (e >> 3) & 63;
        int sg = e >> 9;
        int s = sg % 28;
        int rg = sg / 28;
        int o = rg * 32 + (lane & 31);
        int kk = s * 16 + ((lane >> 5) << 3) + j;
        int kn = kk >> 6;
        int c = kk & 63;
        Wf[e] = f2bf(W[o * KKD + c * KN + kn]);
    }
}

// ---------------------------------------------------------------------------
// Kernel 3: gather + MFMA GEMM, explicit counted-wait pipeline.
// grid 1-D: bid -> b = bid&7 (XCD pin), tile = bid>>3, n0 = tile*256.
// block 256 = 4 waves; wave w: vertices n0+w*64..+63 (2 col tiles), all 64
// outputs (2 rg tiles); 16 MFMA (32x32x16) per k.
// LDS: G[2][256][128B] gather (swizzled via source), WL[2][8KB] W slice.
// One raw s_barrier per k; vmcnt(0) issued AFTER the compute phase so the
// k+1 staging loads overlap k's MFMAs (no __syncthreads full-drain).
// ---------------------------------------------------------------------------
__global__ __launch_bounds__(256, 2) void conv_mfma(
    const u16* __restrict__ xT, const u16* __restrict__ Wf,
    const int* __restrict__ idx, const float* __restrict__ bias,
    float* __restrict__ out) {
    __shared__ alignas(16) u16 G[2][256 * 64];   // 2 x 32 KB
    __shared__ alignas(16) u16 WL[2][4096];      // 2 x 8 KB

    const int bid = blockIdx.x;
    const int b = bid & 7;
    const int n0 = (bid >> 3) * 256;
    const int t = threadIdx.x;
    const int lane = t & 63;
    const int w = t >> 6;
    const int col = lane & 31;
    const int half = lane >> 5;

    const char* xbc = (const char*)(xT + (size_t)b * NV * CI);
    const char* wfc = (const char*)Wf;

    // staging geometry: thread t stages 16B chunk q of rows sr+32*i, i=0..7
    const int sr = t >> 3;                 // 0..31
    const int q = t & 7;
    const int chunk = q ^ (sr & 7);        // source pre-swizzle ((sr+32i)&7 == sr&7)

    int grow[8];
#pragma unroll
    for (int i = 0; i < 8; ++i) {
        int r = n0 + sr + 32 * i;
        grow[i] = (r < NV) ? r : (NV - 1);
    }

    // neighbor indices: j for k=0 now, jnxt for k=1
    int jcur[8], jnxt[8];
#pragma unroll
    for (int i = 0; i < 8; ++i) jcur[i] = idx[(size_t)grow[i] * KN + 0];
#pragma unroll
    for (int i = 0; i < 8; ++i) jnxt[i] = idx[(size_t)grow[i] * KN + 1];

    // prologue: stage k=0 (gather 8x16B + W 2x16B per thread)
    {
        char* gdst = (char*)&G[0][0];
#pragma unroll
        for (int i = 0; i < 8; ++i)
            gload_lds16(xbc + (size_t)jcur[i] * 128 + chunk * 16,
                        gdst + i * 4096 + t * 16);
        char* wdst = (char*)&WL[0][0];
#pragma unroll
        for (int i = 0; i < 2; ++i)
            gload_lds16(wfc + (size_t)(i * 28 + 0) * 1024 + t * 16,
                        wdst + i * 4096 + t * 16);
    }
    asm volatile("s_waitcnt vmcnt(0)" ::: "memory");
    __builtin_amdgcn_sched_barrier(0);
    __builtin_amdgcn_s_barrier();
    asm volatile("" ::: "memory");

    f32x16 acc00{}, acc01{}, acc10{}, acc11{};

    const u32 rmask = ((u32)(col & 7)) << 4;   // (row&7) == (col&7): 32|64 ≡ 0 mod 8
    const u32 row0 = (u32)((w * 64 + col) * 128);
    const u32 row1 = (u32)((w * 64 + 32 + col) * 128);

    for (int k = 0; k < KN; ++k) {
        // ---- issue staging for k+1 (lands under this k's compute) ----
        if (k + 1 < KN) {
            char* gdst = (char*)&G[(k + 1) & 1][0];
#pragma unroll
            for (int i = 0; i < 8; ++i)
                gload_lds16(xbc + (size_t)jnxt[i] * 128 + chunk * 16,
                            gdst + i * 4096 + t * 16);
            char* wdst = (char*)&WL[(k + 1) & 1][0];
#pragma unroll
            for (int i = 0; i < 2; ++i)
                gload_lds16(wfc + (size_t)(i * 28 + (k + 1) * 4) * 1024 + t * 16,
                            wdst + i * 4096 + t * 16);
        }
        // idx for k+2
        if (k + 2 < KN) {
#pragma unroll
            for (int i = 0; i < 8; ++i) jnxt[i] = idx[(size_t)grow[i] * KN + (k + 2)];
        }

        // ---- compute phase on buffers [k&1] ----
        const char* gsrc = (const char*)&G[k & 1][0];
        const char* wsrc = (const char*)&WL[k & 1][0];
#pragma unroll
        for (int sub = 0; sub < 4; ++sub) {
            uint4 a0 = *(const uint4*)(wsrc + (0 * 4 + sub) * 1024 + lane * 16);
            uint4 a1 = *(const uint4*)(wsrc + (1 * 4 + sub) * 1024 + lane * 16);
            u32 boff = ((u32)(sub * 32 + half * 16)) ^ rmask;
            uint4 b0 = *(const uint4*)(gsrc + row0 + boff);
            uint4 b1 = *(const uint4*)(gsrc + row1 + boff);
            acc00 = __builtin_amdgcn_mfma_f32_32x32x16_bf16(
                __builtin_bit_cast(bf16x8, a0), __builtin_bit_cast(bf16x8, b0), acc00, 0, 0, 0);
            acc01 = __builtin_amdgcn_mfma_f32_32x32x16_bf16(
                __builtin_bit_cast(bf16x8, a0), __builtin_bit_cast(bf16x8, b1), acc01, 0, 0, 0);
            acc10 = __builtin_amdgcn_mfma_f32_32x32x16_bf16(
                __builtin_bit_cast(bf16x8, a1), __builtin_bit_cast(bf16x8, b0), acc10, 0, 0, 0);
            acc11 = __builtin_amdgcn_mfma_f32_32x32x16_bf16(
                __builtin_bit_cast(bf16x8, a1), __builtin_bit_cast(bf16x8, b1), acc11, 0, 0, 0);
        }

        // ---- drain my k+1 staging loads, then barrier ----
        asm volatile("s_waitcnt vmcnt(0)" ::: "memory");
        __builtin_amdgcn_sched_barrier(0);
        __builtin_amdgcn_s_barrier();
        asm volatile("" ::: "memory");
    }

    // epilogue: bias + nontemporal store
    const int v0 = n0 + w * 64 + col;
    const int v1 = v0 + 32;
#pragma unroll
    for (int r = 0; r < 16; ++r) {
        int rowo = (r & 3) + 8 * (r >> 2) + 4 * half;
        {
            int o = rowo;                       // rg 0
            float bo = bias[o];
            float* ob = out + ((size_t)b * CO + o) * NV;
            if (v0 < NV) __builtin_nontemporal_store(acc00[r] + bo, ob + v0);
            if (v1 < NV) __builtin_nontemporal_store(acc01[r] + bo, ob + v1);
        }
        {
            int o = 32 + rowo;                  // rg 1
            float bo = bias[o];
            float* ob = out + ((size_t)b * CO + o) * NV;
            if (v0 < NV) __builtin_nontemporal_store(acc10[r] + bo, ob + v0);
            if (v1 < NV) __builtin_nontemporal_store(acc11[r] + bo, ob + v1);
        }
    }
}

// ---------------------------------------------------------------------------
// Fallback (if ws too small): direct fp32 compute, slow but correct.
// ---------------------------------------------------------------------------
__global__ void naive_conv(const float* __restrict__ x, const int* __restrict__ idx,
                           const float* __restrict__ W, const float* __restrict__ bias,
                           float* __restrict__ out) {
    const int b = blockIdx.y;
    const int n = blockIdx.x * 4 + (threadIdx.x & 3);
    const int o = threadIdx.x >> 2;
    if (n >= NV) return;
    float acc = bias[o];
    const float* xb = x + (size_t)b * CI * NV;
    const float* wo = W + o * KKD;
    for (int k = 0; k < KN; ++k) {
        int j = idx[n * KN + k];
        for (int c = 0; c < CI; ++c)
            acc += xb[(size_t)c * NV + j] * wo[c * KN + k];
    }
    out[((size_t)b * CO + o) * NV + n] = acc;
}

// ---------------------------------------------------------------------------
extern "C" void kernel_launch(void* const* d_in, const int* in_sizes, int n_in,
                              void* d_out, int out_size, void* d_ws, size_t ws_size,
                              hipStream_t stream) {
    const float* x    = (const float*)d_in[0];
    const int*   idx  = (const int*)d_in[1];
    const float* W    = (const float*)d_in[2];
    const float* bias = (const float*)d_in[3];
    float* out = (float*)d_out;

    const size_t xT_bytes = (size_t)BB * NV * CI * 2;       // 41,945,088
    const size_t wf_bytes = (size_t)2 * 28 * 64 * 8 * 2;    // 57,344
    const size_t need = xT_bytes + wf_bytes;

    if (ws_size >= need) {
        u16* xT = (u16*)d_ws;
        u16* Wf = (u16*)((char*)d_ws + xT_bytes);
        transpose_x<<<dim3((NV + 63) / 64, BB), 256, 0, stream>>>(x, xT);
        pack_w<<<dim3(112), 256, 0, stream>>>(W, Wf);
        const int ntiles = (NV + 255) / 256;                 // 161
        conv_mfma<<<dim3(ntiles * BB), 256, 0, stream>>>(xT, Wf, idx, bias, out);
    } else {
        naive_conv<<<dim3((NV + 3) / 4, BB), 256, 0, stream>>>(x, idx, W, bias, out);
    }
}

// Round 4
// 102.371 us; speedup vs baseline: 1.0642x; 1.0642x over previous
//
#include <hip/hip_runtime.h>

// Problem constants
#define BB 8
#define CI 64
#define CO 64
#define NV 40962
#define KN 7
#define KKD 448   // CI*KN

typedef unsigned short u16;
typedef unsigned int u32;

typedef __bf16 bf16x8 __attribute__((ext_vector_type(8)));
typedef float f32x16 __attribute__((ext_vector_type(16)));

__device__ inline u16 f2bf(float f) {
    u32 u = __builtin_bit_cast(u32, f);
    u32 r = (u + 0x7FFFu + ((u >> 16) & 1u)) >> 16;  // RNE
    return (u16)r;
}

// ---------------------------------------------------------------------------
// Kernel 1: transpose + bf16 cast:  x[b][c][n] f32  ->  xT[b][n][c] bf16
// ---------------------------------------------------------------------------
__global__ void transpose_x(const float* __restrict__ x, u16* __restrict__ xT) {
    __shared__ u16 tile[64][72];
    const int b = blockIdx.y;
    const int n0 = blockIdx.x * 64;
    const int tid = threadIdx.x;

#pragma unroll
    for (int i = 0; i < 16; ++i) {
        int flat = i * 256 + tid;
        int c = flat >> 6;
        int nn = flat & 63;
        int n = n0 + nn;
        if (n < NV) {
            float v = __builtin_nontemporal_load(&x[((size_t)b * CI + c) * NV + n]);
            tile[nn][c] = f2bf(v);
        }
    }
    __syncthreads();

#pragma unroll
    for (int i = 0; i < 2; ++i) {
        int flat8 = i * 256 + tid;
        int nn = flat8 >> 3;
        int c0 = (flat8 & 7) * 8;
        int n = n0 + nn;
        if (n < NV) {
            uint4 v = *(const uint4*)&tile[nn][c0];
            *(uint4*)&xT[((size_t)b * NV + n) * CI + c0] = v;
        }
    }
}

// ---------------------------------------------------------------------------
// Kernel 2: pack W into MFMA A-fragment order (bf16)
// Wf byte offset (rg*28 + s)*1024 + lane*16, s = k*4 + sub
// ---------------------------------------------------------------------------
__global__ void pack_w(const float* __restrict__ W, u16* __restrict__ Wf) {
    int e = blockIdx.x * 256 + threadIdx.x;
    if (e < 2 * 28 * 64 * 8) {
        int j = e & 7;
        int lane = (e >> 3) & 63;
        int sg = e >> 9;
        int s = sg % 28;
        int rg = sg / 28;
        int o = rg * 32 + (lane & 31);
        int kk = s * 16 + ((lane >> 5) << 3) + j;
        int kn = kk >> 6;
        int c = kk & 63;
        Wf[e] = f2bf(W[o * KKD + c * KN + kn]);
    }
}

// ---------------------------------------------------------------------------
// Kernel 3: barrier-free per-wave pipeline.
// grid 1-D: b = bid&7 (XCD pin), n0 = (bid>>3)*128. block 256 = 4 waves.
// Wave wv owns 32 vertices [n0+wv*32, +32) x all 64 outputs.
// LDS: 4 KB per wave, single-buffered, wave-PRIVATE (no barriers anywhere —
// DS ops are in-order within a wave, so write(k+1)-after-read(k) is safe).
// Per k: issue 4 coalesced gather loads (k+1) to regs -> load 8 A-frags (L2)
// -> 4 ds_read B-frags -> 8 MFMA -> ds_write staged k+1. idx prefetched 2
// ahead via 8-way-broadcast scalar loads. All waits compiler-managed.
// ---------------------------------------------------------------------------
__global__ __launch_bounds__(256, 4) void conv_mfma(
    const u16* __restrict__ xT, const u16* __restrict__ Wf,
    const int* __restrict__ idx, const float* __restrict__ bias,
    float* __restrict__ out) {
    __shared__ alignas(16) u16 G[4][2048];   // 4 waves x 4 KB, wave-private

    const int bid = blockIdx.x;
    const int b = bid & 7;
    const int n0 = (bid >> 3) * 128;
    const int t = threadIdx.x;
    const int lane = t & 63;
    const int wv = t >> 6;
    const int col = lane & 31;
    const int half = lane >> 5;
    const int wrow = lane >> 3;       // 0..7
    const int q = lane & 7;           // 16B chunk in row

    const int vbase = n0 + wv * 32;
    const char* xbc = (const char*)(xT + (size_t)b * NV * CI);
    const char* wfc = (const char*)Wf;
    char* gw = (char*)&G[wv][0];

    // vertices this lane gathers for (instr i covers rows wrow + 8i)
    int vg[4];
#pragma unroll
    for (int i = 0; i < 4; ++i) {
        int v = vbase + wrow + 8 * i;
        vg[i] = (v < NV) ? v : (NV - 1);
    }

    // LDS addresses (XOR swizzle by row&7; wrow==row&7 since rows wrow+8i)
    const u32 wbyte0 = (u32)(wrow * 128) + (u32)((q ^ wrow) << 4);
    u32 rbyte[4];
#pragma unroll
    for (int s = 0; s < 4; ++s)
        rbyte[s] = (u32)(col * 128) + (u32)(((2 * s + half) ^ q) << 4);

    f32x16 acc0{}, acc1{};

    // idx: jcur = k0, jnxt = k1 (kept 1 gather-step + 1 idx-step ahead)
    int jcur[4], jnxt[4];
#pragma unroll
    for (int i = 0; i < 4; ++i) jcur[i] = idx[(size_t)vg[i] * KN + 0];
#pragma unroll
    for (int i = 0; i < 4; ++i) jnxt[i] = idx[(size_t)vg[i] * KN + 1];

    // stage k=0
    {
        uint4 s0[4];
#pragma unroll
        for (int i = 0; i < 4; ++i)
            s0[i] = *(const uint4*)(xbc + (size_t)jcur[i] * 128 + (q << 4));
#pragma unroll
        for (int i = 0; i < 4; ++i)
            *(uint4*)(gw + wbyte0 + (u32)(i * 1024)) = s0[i];
    }

#pragma unroll
    for (int k = 0; k < KN; ++k) {
        // issue gather for k+1 into regs (consumed at loop bottom)
        uint4 stg[4];
        if (k + 1 < KN) {
#pragma unroll
            for (int i = 0; i < 4; ++i)
                stg[i] = *(const uint4*)(xbc + (size_t)jnxt[i] * 128 + (q << 4));
        }
        // idx for k+2
        if (k + 2 < KN) {
#pragma unroll
            for (int i = 0; i < 4; ++i) jnxt[i] = idx[(size_t)vg[i] * KN + (k + 2)];
        }

        // A fragments for this k (L2-resident, lane-linear coalesced)
        uint4 a0[4], a1[4];
#pragma unroll
        for (int s = 0; s < 4; ++s) {
            a0[s] = *(const uint4*)(wfc + (size_t)((0 * 28 + k * 4 + s) * 1024 + lane * 16));
            a1[s] = *(const uint4*)(wfc + (size_t)((1 * 28 + k * 4 + s) * 1024 + lane * 16));
        }

        // B fragments from wave-private LDS + 8 MFMA
#pragma unroll
        for (int s = 0; s < 4; ++s) {
            uint4 bf = *(const uint4*)(gw + rbyte[s]);
            acc0 = __builtin_amdgcn_mfma_f32_32x32x16_bf16(
                __builtin_bit_cast(bf16x8, a0[s]), __builtin_bit_cast(bf16x8, bf), acc0, 0, 0, 0);
            acc1 = __builtin_amdgcn_mfma_f32_32x32x16_bf16(
                __builtin_bit_cast(bf16x8, a1[s]), __builtin_bit_cast(bf16x8, bf), acc1, 0, 0, 0);
        }

        // write staged k+1 after k's reads (same-wave DS ordering, no sync)
        if (k + 1 < KN) {
#pragma unroll
            for (int i = 0; i < 4; ++i)
                *(uint4*)(gw + wbyte0 + (u32)(i * 1024)) = stg[i];
        }
    }

    // epilogue: bias + nontemporal stores
    const int v0 = vbase + col;
    if (v0 < NV) {
        float* ob = out + (size_t)b * CO * NV + v0;
#pragma unroll
        for (int r = 0; r < 16; ++r) {
            int rowo = (r & 3) + 8 * (r >> 2) + 4 * half;
            __builtin_nontemporal_store(acc0[r] + bias[rowo], ob + (size_t)rowo * NV);
            __builtin_nontemporal_store(acc1[r] + bias[32 + rowo], ob + (size_t)(32 + rowo) * NV);
        }
    }
}

// ---------------------------------------------------------------------------
// Fallback (if ws too small): direct fp32 compute, slow but correct.
// ---------------------------------------------------------------------------
__global__ void naive_conv(const float* __restrict__ x, const int* __restrict__ idx,
                           const float* __restrict__ W, const float* __restrict__ bias,
                           float* __restrict__ out) {
    const int b = blockIdx.y;
    const int n = blockIdx.x * 4 + (threadIdx.x & 3);
    const int o = threadIdx.x >> 2;
    if (n >= NV) return;
    float acc = bias[o];
    const float* xb = x + (size_t)b * CI * NV;
    const float* wo = W + o * KKD;
    for (int k = 0; k < KN; ++k) {
        int j = idx[n * KN + k];
        for (int c = 0; c < CI; ++c)
            acc += xb[(size_t)c * NV + j] * wo[c * KN + k];
    }
    out[((size_t)b * CO + o) * NV + n] = acc;
}

// ---------------------------------------------------------------------------
extern "C" void kernel_launch(void* const* d_in, const int* in_sizes, int n_in,
                              void* d_out, int out_size, void* d_ws, size_t ws_size,
                              hipStream_t stream) {
    const float* x    = (const float*)d_in[0];
    const int*   idx  = (const int*)d_in[1];
    const float* W    = (const float*)d_in[2];
    const float* bias = (const float*)d_in[3];
    float* out = (float*)d_out;

    const size_t xT_bytes = (size_t)BB * NV * CI * 2;       // 41,945,088
    const size_t wf_bytes = (size_t)2 * 28 * 64 * 8 * 2;    // 57,344
    const size_t need = xT_bytes + wf_bytes;

    if (ws_size >= need) {
        u16* xT = (u16*)d_ws;
        u16* Wf = (u16*)((char*)d_ws + xT_bytes);
        transpose_x<<<dim3((NV + 63) / 64, BB), 256, 0, stream>>>(x, xT);
        pack_w<<<dim3(112), 256, 0, stream>>>(W, Wf);
        const int ntiles = (NV + 127) / 128;                 // 321
        conv_mfma<<<dim3(ntiles * BB), 256, 0, stream>>>(xT, Wf, idx, bias, out);
    } else {
        naive_conv<<<dim3((NV + 3) / 4, BB), 256, 0, stream>>>(x, idx, W, bias, out);
    }
}

// Round 6
// 80.963 us; speedup vs baseline: 1.3456x; 1.2644x over previous
//
#include <hip/hip_runtime.h>

// Problem constants
#define BB 8
#define CI 64
#define CO 64
#define NV 40962
#define KN 7
#define KKD 448   // CI*KN

typedef unsigned short u16;
typedef unsigned int u32;

typedef __bf16 bf16x8 __attribute__((ext_vector_type(8)));
typedef float f32x16 __attribute__((ext_vector_type(16)));

__device__ inline u16 f2bf(float f) {
    u32 u = __builtin_bit_cast(u32, f);
    u32 r = (u + 0x7FFFu + ((u >> 16) & 1u)) >> 16;  // RNE
    return (u16)r;
}

// global 16B/lane -> LDS at (wave-uniform base + lane*16); dest linear.
__device__ inline void gload_lds16(const void* g, void* l) {
    __builtin_amdgcn_global_load_lds(
        (const __attribute__((address_space(1))) u32*)g,
        (__attribute__((address_space(3))) u32*)l, 16, 0, 0);
}

// ---------------------------------------------------------------------------
// Kernel 1: transpose + bf16 cast:  x[b][c][n] f32  ->  xT[b][n][c] bf16
// ---------------------------------------------------------------------------
__global__ void transpose_x(const float* __restrict__ x, u16* __restrict__ xT) {
    __shared__ u16 tile[64][72];
    const int b = blockIdx.y;
    const int n0 = blockIdx.x * 64;
    const int tid = threadIdx.x;

#pragma unroll
    for (int i = 0; i < 16; ++i) {
        int flat = i * 256 + tid;
        int c = flat >> 6;
        int nn = flat & 63;
        int n = n0 + nn;
        if (n < NV) {
            float v = __builtin_nontemporal_load(&x[((size_t)b * CI + c) * NV + n]);
            tile[nn][c] = f2bf(v);
        }
    }
    __syncthreads();

#pragma unroll
    for (int i = 0; i < 2; ++i) {
        int flat8 = i * 256 + tid;
        int nn = flat8 >> 3;
        int c0 = (flat8 & 7) * 8;
        int n = n0 + nn;
        if (n < NV) {
            uint4 v = *(const uint4*)&tile[nn][c0];
            *(uint4*)&xT[((size_t)b * NV + n) * CI + c0] = v;
        }
    }
}

// ---------------------------------------------------------------------------
// Kernel 2: pack W into MFMA A-fragment order (bf16)
// Wf byte offset (rg*28 + k*4 + sub)*1024 + lane*16
// ---------------------------------------------------------------------------
__global__ void pack_w(const float* __restrict__ W, u16* __restrict__ Wf) {
    int e = blockIdx.x * 256 + threadIdx.x;
    if (e < 2 * 28 * 64 * 8) {
        int j = e & 7;
        int lane = (e >> 3) & 63;
        int sg = e >> 9;
        int s = sg % 28;
        int rg = sg / 28;
        int o = rg * 32 + (lane & 31);
        int kk = s * 16 + ((lane >> 5) << 3) + j;
        int kn = kk >> 6;
        int c = kk & 63;
        Wf[e] = f2bf(W[o * KKD + c * KN + kn]);
    }
}

// ---------------------------------------------------------------------------
// Kernel 3: gather + MFMA GEMM, 3-deep global_load_lds pipeline.
// grid 1-D: b = bid&7 (XCD pin), n0 = (bid>>3)*128. block 512 = 8 waves
// (2 rg x 4 cg); wave = 32 outputs x 32 vertices, 4 MFMA per k.
//
// RACE FIX vs r5: G(k+2) staging is issued AFTER s_barrier(k). Before the
// barrier, sibling waves may still be ds_reading buffer (k+2)%3==(k-1)%3
// (their iter k-1 compute). After the barrier, every wave has issued its
// iter k-1 MFMAs, which required lgkmcnt-completion of those ds_reads.
//
// Per-iter order: issue A(k+1) -> s_waitcnt vmcnt(6) [drains G(k)+A(k),
// leaves G(k+1)+A(k+1)] -> s_barrier -> issue G(k+2) -> compute buf k%3.
// ---------------------------------------------------------------------------
__global__ __launch_bounds__(512, 4) void conv_mfma(
    const u16* __restrict__ xT, const u16* __restrict__ Wf,
    const int* __restrict__ idx, const float* __restrict__ bias,
    float* __restrict__ out) {
    __shared__ alignas(16) u16 G[3][8192];   // 3 x 16 KB

    const int bid = blockIdx.x;
    const int b = bid & 7;
    const int n0 = (bid >> 3) * 128;
    const int t = threadIdx.x;
    const int lane = t & 63;
    const int w = t >> 6;
    const int rg = w & 1;
    const int cg = w >> 1;
    const int col = lane & 31;
    const int half = lane >> 5;

    const char* xbc = (const char*)(xT + (size_t)b * NV * CI);
    const char* wfc = (const char*)Wf;

    // staging geometry: thread t covers rows sr0 and 64+sr0, chunk q
    const int sr0 = t >> 3;                // 0..63
    const int q = t & 7;
    const int qe = q ^ (sr0 & 7);          // source pre-swizzle

    int g0 = n0 + sr0;        if (g0 >= NV) g0 = NV - 1;
    int g1 = n0 + 64 + sr0;   if (g1 >= NV) g1 = NV - 1;

    // all 7 neighbor indices per row (overlapping dwordx4 loads)
    int j0[KN], j1[KN];
    {
        int4 lo0 = *(const int4*)(idx + (size_t)g0 * KN);
        int4 hi0 = *(const int4*)(idx + (size_t)g0 * KN + 3);
        int4 lo1 = *(const int4*)(idx + (size_t)g1 * KN);
        int4 hi1 = *(const int4*)(idx + (size_t)g1 * KN + 3);
        j0[0] = lo0.x; j0[1] = lo0.y; j0[2] = lo0.z; j0[3] = lo0.w;
        j0[4] = hi0.y; j0[5] = hi0.z; j0[6] = hi0.w;
        j1[0] = lo1.x; j1[1] = lo1.y; j1[2] = lo1.z; j1[3] = lo1.w;
        j1[4] = hi1.y; j1[5] = hi1.z; j1[6] = hi1.w;
    }

    // per-wave LDS dest bases (wave-uniform)
    char* gb = (char*)&G[0][0];
    const u32 dst0 = (u32)(w * 1024);            // rows 0..63  slice
    const u32 dst1 = (u32)(8192 + w * 1024);     // rows 64..127 slice

    // B-read geometry
    const int brow = cg * 32 + col;
    const u32 rbase = (u32)(brow * 128);
    const u32 rmask = (u32)(brow & 7) << 4;

    // A-frag addresses
    const u32 abase = (u32)((rg * 28) * 1024 + lane * 16);

    f32x16 acc{};

    // ---- prologue: G(0), A(0), G(1)  (issue order pinned for vmcnt) ----
    gload_lds16(xbc + (size_t)j0[0] * 128 + qe * 16, gb + 0 * 16384 + dst0);
    gload_lds16(xbc + (size_t)j1[0] * 128 + qe * 16, gb + 0 * 16384 + dst1);
    __builtin_amdgcn_sched_barrier(0);
    uint4 acur0 = *(const uint4*)(wfc + abase + 0 * 1024);
    uint4 acur1 = *(const uint4*)(wfc + abase + 1 * 1024);
    uint4 acur2 = *(const uint4*)(wfc + abase + 2 * 1024);
    uint4 acur3 = *(const uint4*)(wfc + abase + 3 * 1024);
    __builtin_amdgcn_sched_barrier(0);
    gload_lds16(xbc + (size_t)j0[1] * 128 + qe * 16, gb + 1 * 16384 + dst0);
    gload_lds16(xbc + (size_t)j1[1] * 128 + qe * 16, gb + 1 * 16384 + dst1);
    __builtin_amdgcn_sched_barrier(0);

#pragma unroll
    for (int k = 0; k < KN; ++k) {
        // ---- issue A(k+1) (pre-barrier; consumed next iter) ----
        uint4 an0, an1, an2, an3;
        if (k + 1 < KN) {
            u32 ab = abase + (u32)((k + 1) * 4 * 1024);
            an0 = *(const uint4*)(wfc + ab + 0 * 1024);
            an1 = *(const uint4*)(wfc + ab + 1 * 1024);
            an2 = *(const uint4*)(wfc + ab + 2 * 1024);
            an3 = *(const uint4*)(wfc + ab + 3 * 1024);
        }
        __builtin_amdgcn_sched_barrier(0);

        // ---- non-draining wait: drains G(k)+A(k), leaves G(k+1)+A(k+1) ----
        if (k <= 5) asm volatile("s_waitcnt vmcnt(6)" ::: "memory");
        else        asm volatile("s_waitcnt vmcnt(0)" ::: "memory");
        __builtin_amdgcn_sched_barrier(0);
        __builtin_amdgcn_s_barrier();
        __builtin_amdgcn_sched_barrier(0);

        // ---- issue G(k+2) AFTER barrier: buffer (k+2)%3's readers (iter
        //      k-1 compute) are provably done once all waves passed barrier k
        if (k + 2 < KN) {
            u32 db = (u32)(((k + 2) % 3) * 16384);
            gload_lds16(xbc + (size_t)j0[k + 2] * 128 + qe * 16, gb + db + dst0);
            gload_lds16(xbc + (size_t)j1[k + 2] * 128 + qe * 16, gb + db + dst1);
        }
        __builtin_amdgcn_sched_barrier(0);

        // ---- compute on buffer k%3 ----
        const char* gsrc = gb + (u32)((k % 3) * 16384);
#pragma unroll
        for (int sub = 0; sub < 4; ++sub) {
            u32 boff = rbase + ((((u32)sub * 32) + (u32)half * 16) ^ rmask);
            uint4 bf = *(const uint4*)(gsrc + boff);
            uint4 af = (sub == 0) ? acur0 : (sub == 1) ? acur1 : (sub == 2) ? acur2 : acur3;
            acc = __builtin_amdgcn_mfma_f32_32x32x16_bf16(
                __builtin_bit_cast(bf16x8, af),
                __builtin_bit_cast(bf16x8, bf), acc, 0, 0, 0);
        }

        if (k + 1 < KN) { acur0 = an0; acur1 = an1; acur2 = an2; acur3 = an3; }
    }

    // epilogue: bias + plain stores
    const int v = n0 + cg * 32 + col;
    if (v < NV) {
        float* ob = out + (size_t)b * CO * NV + v;
#pragma unroll
        for (int r = 0; r < 16; ++r) {
            int rowo = (r & 3) + 8 * (r >> 2) + 4 * half;
            int o = rg * 32 + rowo;
            ob[(size_t)o * NV] = acc[r] + bias[o];
        }
    }
}

// ---------------------------------------------------------------------------
// Fallback (if ws too small): direct fp32 compute, slow but correct.
// ---------------------------------------------------------------------------
__global__ void naive_conv(const float* __restrict__ x, const int* __restrict__ idx,
                           const float* __restrict__ W, const float* __restrict__ bias,
                           float* __restrict__ out) {
    const int b = blockIdx.y;
    const int n = blockIdx.x * 4 + (threadIdx.x & 3);
    const int o = threadIdx.x >> 2;
    if (n >= NV) return;
    float acc = bias[o];
    const float* xb = x + (size_t)b * CI * NV;
    const float* wo = W + o * KKD;
    for (int k = 0; k < KN; ++k) {
        int j = idx[n * KN + k];
        for (int c = 0; c < CI; ++c)
            acc += xb[(size_t)c * NV + j] * wo[c * KN + k];
    }
    out[((size_t)b * CO + o) * NV + n] = acc;
}

// ---------------------------------------------------------------------------
extern "C" void kernel_launch(void* const* d_in, const int* in_sizes, int n_in,
                              void* d_out, int out_size, void* d_ws, size_t ws_size,
                              hipStream_t stream) {
    const float* x    = (const float*)d_in[0];
    const int*   idx  = (const int*)d_in[1];
    const float* W    = (const float*)d_in[2];
    const float* bias = (const float*)d_in[3];
    float* out = (float*)d_out;

    const size_t xT_bytes = (size_t)BB * NV * CI * 2;       // 41,945,088
    const size_t wf_bytes = (size_t)2 * 28 * 64 * 8 * 2;    // 57,344
    const size_t need = xT_bytes + wf_bytes;

    if (ws_size >= need) {
        u16* xT = (u16*)d_ws;
        u16* Wf = (u16*)((char*)d_ws + xT_bytes);
        transpose_x<<<dim3((NV + 63) / 64, BB), 256, 0, stream>>>(x, xT);
        pack_w<<<dim3(112), 256, 0, stream>>>(W, Wf);
        const int ntiles = (NV + 127) / 128;                 // 321
        conv_mfma<<<dim3(ntiles * BB), 512, 0, stream>>>(xT, Wf, idx, bias, out);
    } else {
        naive_conv<<<dim3((NV + 3) / 4, BB), 256, 0, stream>>>(x, idx, W, bias, out);
    }
}

// Round 7
// 79.341 us; speedup vs baseline: 1.3731x; 1.0204x over previous
//
#include <hip/hip_runtime.h>

// Problem constants
#define BB 8
#define CI 64
#define CO 64
#define NV 40962
#define KN 7
#define KKD 448   // CI*KN

typedef unsigned short u16;
typedef unsigned int u32;

typedef __bf16 bf16x8 __attribute__((ext_vector_type(8)));
typedef float f32x16 __attribute__((ext_vector_type(16)));

__device__ inline u16 f2bf(float f) {
    u32 u = __builtin_bit_cast(u32, f);
    u32 r = (u + 0x7FFFu + ((u >> 16) & 1u)) >> 16;  // RNE
    return (u16)r;
}

// global 16B/lane -> LDS at (wave-uniform base + lane*16); dest linear.
__device__ inline void gload_lds16(const void* g, void* l) {
    __builtin_amdgcn_global_load_lds(
        (const __attribute__((address_space(1))) u32*)g,
        (__attribute__((address_space(3))) u32*)l, 16, 0, 0);
}

// ---------------------------------------------------------------------------
// Kernel 1: transpose + bf16 cast:  x[b][c][n] f32  ->  xT[b][n][c] bf16
// ---------------------------------------------------------------------------
__global__ void transpose_x(const float* __restrict__ x, u16* __restrict__ xT) {
    __shared__ u16 tile[64][72];
    const int b = blockIdx.y;
    const int n0 = blockIdx.x * 64;
    const int tid = threadIdx.x;

#pragma unroll
    for (int i = 0; i < 16; ++i) {
        int flat = i * 256 + tid;
        int c = flat >> 6;
        int nn = flat & 63;
        int n = n0 + nn;
        if (n < NV) {
            float v = __builtin_nontemporal_load(&x[((size_t)b * CI + c) * NV + n]);
            tile[nn][c] = f2bf(v);
        }
    }
    __syncthreads();

#pragma unroll
    for (int i = 0; i < 2; ++i) {
        int flat8 = i * 256 + tid;
        int nn = flat8 >> 3;
        int c0 = (flat8 & 7) * 8;
        int n = n0 + nn;
        if (n < NV) {
            uint4 v = *(const uint4*)&tile[nn][c0];
            *(uint4*)&xT[((size_t)b * NV + n) * CI + c0] = v;
        }
    }
}

// ---------------------------------------------------------------------------
// Kernel 2: pack W into MFMA A-fragment order (bf16)
// Wf byte offset (rg*28 + k*4 + sub)*1024 + lane*16
// ---------------------------------------------------------------------------
__global__ void pack_w(const float* __restrict__ W, u16* __restrict__ Wf) {
    int e = blockIdx.x * 256 + threadIdx.x;
    if (e < 2 * 28 * 64 * 8) {
        int j = e & 7;
        int lane = (e >> 3) & 63;
        int sg = e >> 9;
        int s = sg % 28;
        int rg = sg / 28;
        int o = rg * 32 + (lane & 31);
        int kk = s * 16 + ((lane >> 5) << 3) + j;
        int kn = kk >> 6;
        int c = kk & 63;
        Wf[e] = f2bf(W[o * KKD + c * KN + kn]);
    }
}

// ---------------------------------------------------------------------------
// Kernel 3: gather + MFMA GEMM, 3-deep global_load_lds pipeline.
// OCCUPANCY EXPERIMENT vs r6: identical schedule, 3x smaller granularity.
// grid 1-D: b = bid&7 (XCD pin), n0 = (bid>>3)*64. block 256 = 4 waves
// (2 rg x 2 cg); wave = 32 outputs x 32 vertices, 4 MFMA per k.
// LDS: G[3][8KB] ring (24 KB total) -> up to 6 blocks/CU; VGPR cap 85 via
// __launch_bounds__(256,6) -> ~24 waves/CU (75%) vs r6's 16 (50%).
//
// Schedule per iter k (proven race-free in r6):
//   issue A(k+1) -> vmcnt(6) [drains G(k)+A(k), leaves G(k+1)+A(k+1)]
//   -> s_barrier -> issue G(k+2) into buf (k+2)%3 (readers finished at
//   barrier) -> compute buf k%3.
// ---------------------------------------------------------------------------
__global__ __launch_bounds__(256, 6) void conv_mfma(
    const u16* __restrict__ xT, const u16* __restrict__ Wf,
    const int* __restrict__ idx, const float* __restrict__ bias,
    float* __restrict__ out) {
    __shared__ alignas(16) u16 G[3][4096];   // 3 x 8 KB

    const int bid = blockIdx.x;
    const int b = bid & 7;
    const int n0 = (bid >> 3) * 64;
    const int t = threadIdx.x;
    const int lane = t & 63;
    const int w = t >> 6;        // 0..3
    const int rg = w & 1;
    const int cg = w >> 1;       // 0..1
    const int col = lane & 31;
    const int half = lane >> 5;

    const char* xbc = (const char*)(xT + (size_t)b * NV * CI);
    const char* wfc = (const char*)Wf;

    // staging geometry: thread t covers rows sr0 and 32+sr0, chunk q
    const int sr0 = t >> 3;                // 0..31
    const int q = t & 7;
    const int qe = q ^ (sr0 & 7);          // source pre-swizzle ((sr0+32)&7 == sr0&7)

    int g0 = n0 + sr0;        if (g0 >= NV) g0 = NV - 1;
    int g1 = n0 + 32 + sr0;   if (g1 >= NV) g1 = NV - 1;

    // all 7 neighbor indices per row (overlapping dwordx4 loads)
    int j0[KN], j1[KN];
    {
        int4 lo0 = *(const int4*)(idx + (size_t)g0 * KN);
        int4 hi0 = *(const int4*)(idx + (size_t)g0 * KN + 3);
        int4 lo1 = *(const int4*)(idx + (size_t)g1 * KN);
        int4 hi1 = *(const int4*)(idx + (size_t)g1 * KN + 3);
        j0[0] = lo0.x; j0[1] = lo0.y; j0[2] = lo0.z; j0[3] = lo0.w;
        j0[4] = hi0.y; j0[5] = hi0.z; j0[6] = hi0.w;
        j1[0] = lo1.x; j1[1] = lo1.y; j1[2] = lo1.z; j1[3] = lo1.w;
        j1[4] = hi1.y; j1[5] = hi1.z; j1[6] = hi1.w;
    }

    // per-wave LDS dest bases (wave-uniform); buffer = 64 rows x 128 B
    char* gb = (char*)&G[0][0];
    const u32 dst0 = (u32)(w * 1024);            // rows 0..31 slice
    const u32 dst1 = (u32)(4096 + w * 1024);     // rows 32..63 slice

    // B-read geometry
    const int brow = cg * 32 + col;              // 0..63
    const u32 rbase = (u32)(brow * 128);
    const u32 rmask = (u32)(brow & 7) << 4;

    // A-frag addresses
    const u32 abase = (u32)((rg * 28) * 1024 + lane * 16);

    f32x16 acc{};

    // ---- prologue: G(0), A(0), G(1)  (issue order pinned for vmcnt) ----
    gload_lds16(xbc + (size_t)j0[0] * 128 + qe * 16, gb + 0 * 8192 + dst0);
    gload_lds16(xbc + (size_t)j1[0] * 128 + qe * 16, gb + 0 * 8192 + dst1);
    __builtin_amdgcn_sched_barrier(0);
    uint4 acur0 = *(const uint4*)(wfc + abase + 0 * 1024);
    uint4 acur1 = *(const uint4*)(wfc + abase + 1 * 1024);
    uint4 acur2 = *(const uint4*)(wfc + abase + 2 * 1024);
    uint4 acur3 = *(const uint4*)(wfc + abase + 3 * 1024);
    __builtin_amdgcn_sched_barrier(0);
    gload_lds16(xbc + (size_t)j0[1] * 128 + qe * 16, gb + 1 * 8192 + dst0);
    gload_lds16(xbc + (size_t)j1[1] * 128 + qe * 16, gb + 1 * 8192 + dst1);
    __builtin_amdgcn_sched_barrier(0);

#pragma unroll
    for (int k = 0; k < KN; ++k) {
        // ---- issue A(k+1) (pre-barrier; consumed next iter) ----
        uint4 an0, an1, an2, an3;
        if (k + 1 < KN) {
            u32 ab = abase + (u32)((k + 1) * 4 * 1024);
            an0 = *(const uint4*)(wfc + ab + 0 * 1024);
            an1 = *(const uint4*)(wfc + ab + 1 * 1024);
            an2 = *(const uint4*)(wfc + ab + 2 * 1024);
            an3 = *(const uint4*)(wfc + ab + 3 * 1024);
        }
        __builtin_amdgcn_sched_barrier(0);

        // ---- non-draining wait: drains G(k)+A(k), leaves G(k+1)+A(k+1) ----
        if (k <= 5) asm volatile("s_waitcnt vmcnt(6)" ::: "memory");
        else        asm volatile("s_waitcnt vmcnt(0)" ::: "memory");
        __builtin_amdgcn_sched_barrier(0);
        __builtin_amdgcn_s_barrier();
        __builtin_amdgcn_sched_barrier(0);

        // ---- issue G(k+2) AFTER barrier: buffer (k+2)%3's readers (iter
        //      k-1 compute) are provably done once all waves passed barrier k
        if (k + 2 < KN) {
            u32 db = (u32)(((k + 2) % 3) * 8192);
            gload_lds16(xbc + (size_t)j0[k + 2] * 128 + qe * 16, gb + db + dst0);
            gload_lds16(xbc + (size_t)j1[k + 2] * 128 + qe * 16, gb + db + dst1);
        }
        __builtin_amdgcn_sched_barrier(0);

        // ---- compute on buffer k%3 ----
        const char* gsrc = gb + (u32)((k % 3) * 8192);
#pragma unroll
        for (int sub = 0; sub < 4; ++sub) {
            u32 boff = rbase + ((((u32)sub * 32) + (u32)half * 16) ^ rmask);
            uint4 bf = *(const uint4*)(gsrc + boff);
            uint4 af = (sub == 0) ? acur0 : (sub == 1) ? acur1 : (sub == 2) ? acur2 : acur3;
            acc = __builtin_amdgcn_mfma_f32_32x32x16_bf16(
                __builtin_bit_cast(bf16x8, af),
                __builtin_bit_cast(bf16x8, bf), acc, 0, 0, 0);
        }

        if (k + 1 < KN) { acur0 = an0; acur1 = an1; acur2 = an2; acur3 = an3; }
    }

    // epilogue: bias + plain stores
    const int v = n0 + cg * 32 + col;
    if (v < NV) {
        float* ob = out + (size_t)b * CO * NV + v;
#pragma unroll
        for (int r = 0; r < 16; ++r) {
            int rowo = (r & 3) + 8 * (r >> 2) + 4 * half;
            int o = rg * 32 + rowo;
            ob[(size_t)o * NV] = acc[r] + bias[o];
        }
    }
}

// ---------------------------------------------------------------------------
// Fallback (if ws too small): direct fp32 compute, slow but correct.
// ---------------------------------------------------------------------------
__global__ void naive_conv(const float* __restrict__ x, const int* __restrict__ idx,
                           const float* __restrict__ W, const float* __restrict__ bias,
                           float* __restrict__ out) {
    const int b = blockIdx.y;
    const int n = blockIdx.x * 4 + (threadIdx.x & 3);
    const int o = threadIdx.x >> 2;
    if (n >= NV) return;
    float acc = bias[o];
    const float* xb = x + (size_t)b * CI * NV;
    const float* wo = W + o * KKD;
    for (int k = 0; k < KN; ++k) {
        int j = idx[n * KN + k];
        for (int c = 0; c < CI; ++c)
            acc += xb[(size_t)c * NV + j] * wo[c * KN + k];
    }
    out[((size_t)b * CO + o) * NV + n] = acc;
}

// ---------------------------------------------------------------------------
extern "C" void kernel_launch(void* const* d_in, const int* in_sizes, int n_in,
                              void* d_out, int out_size, void* d_ws, size_t ws_size,
                              hipStream_t stream) {
    const float* x    = (const float*)d_in[0];
    const int*   idx  = (const int*)d_in[1];
    const float* W    = (const float*)d_in[2];
    const float* bias = (const float*)d_in[3];
    float* out = (float*)d_out;

    const size_t xT_bytes = (size_t)BB * NV * CI * 2;       // 41,945,088
    const size_t wf_bytes = (size_t)2 * 28 * 64 * 8 * 2;    // 57,344
    const size_t need = xT_bytes + wf_bytes;

    if (ws_size >= need) {
        u16* xT = (u16*)d_ws;
        u16* Wf = (u16*)((char*)d_ws + xT_bytes);
        transpose_x<<<dim3((NV + 63) / 64, BB), 256, 0, stream>>>(x, xT);
        pack_w<<<dim3(112), 256, 0, stream>>>(W, Wf);
        const int ntiles = (NV + 63) / 64;                   // 641
        conv_mfma<<<dim3(ntiles * BB), 256, 0, stream>>>(xT, Wf, idx, bias, out);
    } else {
        naive_conv<<<dim3((NV + 3) / 4, BB), 256, 0, stream>>>(x, idx, W, bias, out);
    }
}